// Round 5
// baseline (793.466 us; speedup 1.0000x reference)
//
#include <hip/hip_runtime.h>
#include <math.h>

#define NB   4
#define NT   500
#define NF   65
#define NC   128
#define NH   8
#define NE   4
#define NV   16
#define NCTX 10
#define DQ   260    // NF*NE
#define DV   1040   // NF*NV
#define DP   8320   // NF*NC

// murs layout offsets (floats): [muQ rsQ muK rsK muV rsV], each 32*500
#define MQ 0
#define RQ 16000
#define MK 32000
#define RK 48000
#define MV 64000
#define RV 80000

// Wt workspace layout (floats): [WtQ 128x32][WtK 128x32][WtV 128x128][WtP 128x128]
#define WTQ 0
#define WTK 4096
#define WTV 8192
#define WTP 24576

// ---------------- one-shot weight transpose into workspace: Wt[c][o] ----------------
__global__ __launch_bounds__(256) void transW_k(const float* __restrict__ WQ,
    const float* __restrict__ WK, const float* __restrict__ WV,
    const float* __restrict__ WP, float* __restrict__ Wt)
{
    int i = blockIdx.x * 256 + threadIdx.x;
    if (i < 4096) {
        int c = i >> 5, o = i & 31;
        Wt[WTQ + c * 32 + o] = WQ[o * 128 + c];
    } else if (i < 8192) {
        int j = i - 4096; int c = j >> 5, o = j & 31;
        Wt[WTK + c * 32 + o] = WK[o * 128 + c];
    } else if (i < 24576) {
        int j = i - 8192; int c = j >> 7, o = j & 127;
        Wt[WTV + c * 128 + o] = WV[o * 128 + c];
    } else if (i < 40960) {
        int j = i - 24576; int c = j >> 7, o = j & 127;
        Wt[WTP + c * 128 + o] = WP[o * 128 + c];
    }
}

// ---------------- Q/K projection, LDS-tiled GEMM: 128c -> 32o over 64t ----------------
// Block 256 thr: stage x-tile [128c][64t] (32KB) + W-tile [128c][32o] (16KB); inner loop pure LDS.
// Thread: tt=tid&15 (4 t), og=tid>>4 (2 o). Output [bh][d=f*4+e][t] + atomic LN stats.
__global__ __launch_bounds__(256, 2) void proj32_k(const float* __restrict__ x,
    const float* __restrict__ Wt, const float* __restrict__ bias,
    const float* __restrict__ a, float* __restrict__ out,
    float* __restrict__ sS, float* __restrict__ sS2)
{
    __shared__ float Xl[128 * 64];
    __shared__ float Wl[128 * 32];
    int b = blockIdx.x / NF, f = blockIdx.x % NF;
    int t0n = blockIdx.y * 64;
    int t0c = t0n <= NT - 64 ? t0n : NT - 64;   // 436 for last chunk
    int skipmin = t0n - t0c;                     // 12 for last chunk else 0
    const size_t xs = (size_t)NF * NT;
    const float* xb = x + (size_t)(b * NC) * xs + (size_t)f * NT + t0c;
#pragma unroll
    for (int k = 0; k < 8; k++) {               // x: 2048 float4
        int q = threadIdx.x + k * 256;
        int c = q >> 4, tc = (q & 15) * 4;
        *(float4*)(Xl + q * 4) = *(const float4*)(xb + (size_t)c * xs + tc);
    }
#pragma unroll
    for (int k = 0; k < 4; k++) {               // w: 1024 float4, row stride 32
        int q = threadIdx.x + k * 256;
        int c = q >> 3, col = (q & 7) * 4;
        *(float4*)(Wl + q * 4) = *(const float4*)(Wt + c * 32 + col);
    }
    __syncthreads();
    int tt = threadIdx.x & 15;
    int og = threadIdx.x >> 4;                  // 0..15 -> o = og*2 + j
    float4 acc0 = make_float4(0.f, 0.f, 0.f, 0.f);
    float4 acc1 = make_float4(0.f, 0.f, 0.f, 0.f);
    const float* xr = Xl + tt * 4;
    const float* wr = Wl + og * 2;
#pragma unroll 8
    for (int c = 0; c < NC; c++) {
        float4 x4 = *(const float4*)(xr + c * 64);
        float2 w2 = *(const float2*)(wr + c * 32);
        acc0.x += w2.x * x4.x; acc0.y += w2.x * x4.y; acc0.z += w2.x * x4.z; acc0.w += w2.x * x4.w;
        acc1.x += w2.y * x4.x; acc1.y += w2.y * x4.y; acc1.z += w2.y * x4.z; acc1.w += w2.y * x4.w;
    }
    if (tt * 4 < skipmin) return;
    float av = a[0];
    int t0 = t0c + tt * 4;
    float s0 = 0.f, s1 = 0.f, s2 = 0.f, s3 = 0.f;
    float q0 = 0.f, q1 = 0.f, q2 = 0.f, q3 = 0.f;
#pragma unroll
    for (int j = 0; j < 2; j++) {
        int o = og * 2 + j;
        float bo = bias[o];
        float4 v = j == 0 ? acc0 : acc1;
        v.x += bo; v.y += bo; v.z += bo; v.w += bo;
        v.x = v.x >= 0.f ? v.x : av * v.x;
        v.y = v.y >= 0.f ? v.y : av * v.y;
        v.z = v.z >= 0.f ? v.z : av * v.z;
        v.w = v.w >= 0.f ? v.w : av * v.w;
        int h = o >> 2, e = o & 3;
        *(float4*)(out + ((size_t)(b * NH + h) * DQ + f * NE + e) * NT + t0) = v;
        s0 += v.x; s1 += v.y; s2 += v.z; s3 += v.w;
        q0 += v.x * v.x; q1 += v.y * v.y; q2 += v.z * v.z; q3 += v.w * v.w;
    }
    // reduce og pairs (xor 16): combines 2+2 o = one head's 4 o
    s0 += __shfl_xor(s0, 16); s1 += __shfl_xor(s1, 16);
    s2 += __shfl_xor(s2, 16); s3 += __shfl_xor(s3, 16);
    q0 += __shfl_xor(q0, 16); q1 += __shfl_xor(q1, 16);
    q2 += __shfl_xor(q2, 16); q3 += __shfl_xor(q3, 16);
    if ((threadIdx.x & 16) == 0) {
        int h = og >> 1;
        int base = (b * NH + h) * NT + t0;
        atomicAdd(&sS[base],     s0); atomicAdd(&sS[base + 1], s1);
        atomicAdd(&sS[base + 2], s2); atomicAdd(&sS[base + 3], s3);
        atomicAdd(&sS2[base],     q0); atomicAdd(&sS2[base + 1], q1);
        atomicAdd(&sS2[base + 2], q2); atomicAdd(&sS2[base + 3], q3);
    }
}

// ---------------- V projection, LDS-tiled GEMM: 128c -> 64o (z-chunk) over 64t ----------------
// Thread: tt=tid&15 (4 t), og=tid>>4 (4 o). Wave = exactly one head. Output [bh][d=f*16+v][t].
__global__ __launch_bounds__(256, 2) void projV_k(const float* __restrict__ x,
    const float* __restrict__ Wt, const float* __restrict__ bias,
    const float* __restrict__ a, float* __restrict__ out,
    float* __restrict__ sS, float* __restrict__ sS2)
{
    __shared__ float Xl[128 * 64];
    __shared__ float Wl[128 * 64];
    int b = blockIdx.x / NF, f = blockIdx.x % NF;
    int oc = blockIdx.z * 64;
    int t0n = blockIdx.y * 64;
    int t0c = t0n <= NT - 64 ? t0n : NT - 64;
    int skipmin = t0n - t0c;
    const size_t xs = (size_t)NF * NT;
    const float* xb = x + (size_t)(b * NC) * xs + (size_t)f * NT + t0c;
    const float* wb = Wt + oc;                  // row stride 128
#pragma unroll
    for (int k = 0; k < 8; k++) {
        int q = threadIdx.x + k * 256;
        int c = q >> 4, tc = (q & 15) * 4;
        *(float4*)(Xl + q * 4) = *(const float4*)(xb + (size_t)c * xs + tc);
    }
#pragma unroll
    for (int k = 0; k < 8; k++) {
        int q = threadIdx.x + k * 256;
        int c = q >> 4, col = (q & 15) * 4;
        *(float4*)(Wl + q * 4) = *(const float4*)(wb + c * 128 + col);
    }
    __syncthreads();
    int tt = threadIdx.x & 15;
    int og = threadIdx.x >> 4;                  // 0..15 -> o = oc + og*4 + j
    float4 acc0 = make_float4(0.f, 0.f, 0.f, 0.f);
    float4 acc1 = make_float4(0.f, 0.f, 0.f, 0.f);
    float4 acc2 = make_float4(0.f, 0.f, 0.f, 0.f);
    float4 acc3 = make_float4(0.f, 0.f, 0.f, 0.f);
    const float* xr = Xl + tt * 4;
    const float* wr = Wl + og * 4;
#pragma unroll 8
    for (int c = 0; c < NC; c++) {
        float4 x4 = *(const float4*)(xr + c * 64);
        float4 w4 = *(const float4*)(wr + c * 64);
        acc0.x += w4.x * x4.x; acc0.y += w4.x * x4.y; acc0.z += w4.x * x4.z; acc0.w += w4.x * x4.w;
        acc1.x += w4.y * x4.x; acc1.y += w4.y * x4.y; acc1.z += w4.y * x4.z; acc1.w += w4.y * x4.w;
        acc2.x += w4.z * x4.x; acc2.y += w4.z * x4.y; acc2.z += w4.z * x4.z; acc2.w += w4.z * x4.w;
        acc3.x += w4.w * x4.x; acc3.y += w4.w * x4.y; acc3.z += w4.w * x4.z; acc3.w += w4.w * x4.w;
    }
    if (tt * 4 < skipmin) return;
    float av = a[0];
    int t0 = t0c + tt * 4;
    int h = (oc + og * 4) >> 4;
    float s0 = 0.f, s1 = 0.f, s2 = 0.f, s3 = 0.f;
    float q0 = 0.f, q1 = 0.f, q2 = 0.f, q3 = 0.f;
#pragma unroll
    for (int j = 0; j < 4; j++) {
        int o = oc + og * 4 + j;
        float bo = bias[o];
        float4 v = j == 0 ? acc0 : j == 1 ? acc1 : j == 2 ? acc2 : acc3;
        v.x += bo; v.y += bo; v.z += bo; v.w += bo;
        v.x = v.x >= 0.f ? v.x : av * v.x;
        v.y = v.y >= 0.f ? v.y : av * v.y;
        v.z = v.z >= 0.f ? v.z : av * v.z;
        v.w = v.w >= 0.f ? v.w : av * v.w;
        *(float4*)(out + ((size_t)(b * NH + h) * DV + f * NV + (o & 15)) * NT + t0) = v;
        s0 += v.x; s1 += v.y; s2 += v.z; s3 += v.w;
        q0 += v.x * v.x; q1 += v.y * v.y; q2 += v.z * v.z; q3 += v.w * v.w;
    }
    // reduce over 4 og-subgroups (xor 16, 32): lanes 0-15 of wave hold full head sum
    s0 += __shfl_xor(s0, 16); s1 += __shfl_xor(s1, 16);
    s2 += __shfl_xor(s2, 16); s3 += __shfl_xor(s3, 16);
    q0 += __shfl_xor(q0, 16); q1 += __shfl_xor(q1, 16);
    q2 += __shfl_xor(q2, 16); q3 += __shfl_xor(q3, 16);
    s0 += __shfl_xor(s0, 32); s1 += __shfl_xor(s1, 32);
    s2 += __shfl_xor(s2, 32); s3 += __shfl_xor(s3, 32);
    q0 += __shfl_xor(q0, 32); q1 += __shfl_xor(q1, 32);
    q2 += __shfl_xor(q2, 32); q3 += __shfl_xor(q3, 32);
    if ((threadIdx.x & 48) == 0) {
        int base = (b * NH + h) * NT + t0;
        atomicAdd(&sS[base],     s0); atomicAdd(&sS[base + 1], s1);
        atomicAdd(&sS[base + 2], s2); atomicAdd(&sS[base + 3], s3);
        atomicAdd(&sS2[base],     q0); atomicAdd(&sS2[base + 1], q1);
        atomicAdd(&sS2[base + 2], q2); atomicAdd(&sS2[base + 3], q3);
    }
}

// ---------------- P projection, LDS-tiled GEMM: VoT 128c -> 64o (z-chunk) over 64t ----------------
__global__ __launch_bounds__(256, 2) void projP_k(const float* __restrict__ VoT,
    const float* __restrict__ Wt, const float* __restrict__ bias,
    const float* __restrict__ a, float* __restrict__ yraw,
    float* __restrict__ sP, float* __restrict__ s2P)
{
    __shared__ float Xl[128 * 64];
    __shared__ float Wl[128 * 64];
    int b = blockIdx.x / NF, f = blockIdx.x % NF;
    int oc = blockIdx.z * 64;
    int t0n = blockIdx.y * 64;
    int t0c = t0n <= NT - 64 ? t0n : NT - 64;
    int skipmin = t0n - t0c;
    const float* zb = VoT + ((size_t)(b * NH) * DV + f * NV) * NT + t0c;
    const float* wb = Wt + oc;
#pragma unroll
    for (int k = 0; k < 8; k++) {               // rows r: c = h*16+v
        int q = threadIdx.x + k * 256;
        int r = q >> 4, tc = (q & 15) * 4;
        const float* src = zb + ((size_t)(r >> 4) * DV + (r & 15)) * NT + tc;
        *(float4*)(Xl + q * 4) = *(const float4*)src;
    }
#pragma unroll
    for (int k = 0; k < 8; k++) {
        int q = threadIdx.x + k * 256;
        int c = q >> 4, col = (q & 15) * 4;
        *(float4*)(Wl + q * 4) = *(const float4*)(wb + c * 128 + col);
    }
    __syncthreads();
    int tt = threadIdx.x & 15;
    int og = threadIdx.x >> 4;
    float4 acc0 = make_float4(0.f, 0.f, 0.f, 0.f);
    float4 acc1 = make_float4(0.f, 0.f, 0.f, 0.f);
    float4 acc2 = make_float4(0.f, 0.f, 0.f, 0.f);
    float4 acc3 = make_float4(0.f, 0.f, 0.f, 0.f);
    const float* xr = Xl + tt * 4;
    const float* wr = Wl + og * 4;
#pragma unroll 8
    for (int c = 0; c < NC; c++) {
        float4 x4 = *(const float4*)(xr + c * 64);
        float4 w4 = *(const float4*)(wr + c * 64);
        acc0.x += w4.x * x4.x; acc0.y += w4.x * x4.y; acc0.z += w4.x * x4.z; acc0.w += w4.x * x4.w;
        acc1.x += w4.y * x4.x; acc1.y += w4.y * x4.y; acc1.z += w4.y * x4.z; acc1.w += w4.y * x4.w;
        acc2.x += w4.z * x4.x; acc2.y += w4.z * x4.y; acc2.z += w4.z * x4.z; acc2.w += w4.z * x4.w;
        acc3.x += w4.w * x4.x; acc3.y += w4.w * x4.y; acc3.z += w4.w * x4.z; acc3.w += w4.w * x4.w;
    }
    if (tt * 4 < skipmin) return;
    float av = a[0];
    int t0 = t0c + tt * 4;
    float s0 = 0.f, s1 = 0.f, s2 = 0.f, s3 = 0.f;
    float q0 = 0.f, q1 = 0.f, q2 = 0.f, q3 = 0.f;
#pragma unroll
    for (int j = 0; j < 4; j++) {
        int o = oc + og * 4 + j;
        float bo = bias[o];
        float4 v = j == 0 ? acc0 : j == 1 ? acc1 : j == 2 ? acc2 : acc3;
        v.x += bo; v.y += bo; v.z += bo; v.w += bo;
        v.x = v.x >= 0.f ? v.x : av * v.x;
        v.y = v.y >= 0.f ? v.y : av * v.y;
        v.z = v.z >= 0.f ? v.z : av * v.z;
        v.w = v.w >= 0.f ? v.w : av * v.w;
        *(float4*)(yraw + ((size_t)(b * NC + o) * NF + f) * NT + t0) = v;
        s0 += v.x; s1 += v.y; s2 += v.z; s3 += v.w;
        q0 += v.x * v.x; q1 += v.y * v.y; q2 += v.z * v.z; q3 += v.w * v.w;
    }
    s0 += __shfl_xor(s0, 16); s1 += __shfl_xor(s1, 16);
    s2 += __shfl_xor(s2, 16); s3 += __shfl_xor(s3, 16);
    q0 += __shfl_xor(q0, 16); q1 += __shfl_xor(q1, 16);
    q2 += __shfl_xor(q2, 16); q3 += __shfl_xor(q3, 16);
    s0 += __shfl_xor(s0, 32); s1 += __shfl_xor(s1, 32);
    s2 += __shfl_xor(s2, 32); s3 += __shfl_xor(s3, 32);
    q0 += __shfl_xor(q0, 32); q1 += __shfl_xor(q1, 32);
    q2 += __shfl_xor(q2, 32); q3 += __shfl_xor(q3, 32);
    if ((threadIdx.x & 48) == 0) {
        int base = b * NT + t0;
        atomicAdd(&sP[base],     s0); atomicAdd(&sP[base + 1], s1);
        atomicAdd(&sP[base + 2], s2); atomicAdd(&sP[base + 3], s3);
        atomicAdd(&s2P[base],     q0); atomicAdd(&s2P[base + 1], q1);
        atomicAdd(&s2P[base + 2], q2); atomicAdd(&s2P[base + 3], q3);
    }
}

// ---------------- finalize QKV stats -> mu/rs ----------------
__global__ __launch_bounds__(256) void finqkv_k(const float* __restrict__ stats,
    float* __restrict__ murs)
{
    int i = blockIdx.x * 256 + threadIdx.x;
    if (i >= 48000) return;
    int seg = i / 16000, j = i % 16000;
    float S = stats[seg * 32000 + j], S2 = stats[seg * 32000 + 16000 + j];
    float D = (seg < 2) ? 260.f : 1040.f;
    float mu = S / D;
    float var = S2 / D - mu * mu;
    murs[seg * 32000 + j] = mu;
    murs[seg * 32000 + 16000 + j] = rsqrtf(var + 1e-5f);
}

__global__ __launch_bounds__(256) void finp_k(const float* __restrict__ sP,
    const float* __restrict__ s2P, float* __restrict__ muP, float* __restrict__ rsP)
{
    int i = blockIdx.x * 256 + threadIdx.x;
    if (i >= NB * NT) return;
    float inv = 1.0f / (float)DP;
    float mu = sP[i] * inv;
    float var = s2P[i] * inv - mu * mu;
    muP[i] = mu;
    rsP[i] = rsqrtf(var + 1e-5f);
}

// ---------------- K_buf_new / V_buf_new: LN applied on the fly ----------------
__global__ void copybuf_k(const float* __restrict__ Kt, const float* __restrict__ Vt,
    const float* __restrict__ murs,
    const float* __restrict__ g_K, const float* __restrict__ be_K,
    const float* __restrict__ g_V, const float* __restrict__ be_V,
    float* __restrict__ outK, float* __restrict__ outV)
{
    int i = blockIdx.x * 256 + threadIdx.x;
    const int NK = 32 * 9 * DQ;
    const int NVb = 32 * 9 * DV;
    if (i < NK) {
        int bh = i / (9 * DQ); int r = i % (9 * DQ); int j = r / DQ; int d = r % DQ;
        int tt = 491 + j;
        float v = Kt[(size_t)(bh * DQ + d) * NT + tt];
        float mu = murs[MK + bh * NT + tt], rs = murs[RK + bh * NT + tt];
        outK[i] = (v - mu) * rs * g_K[d] + be_K[d];
    } else if (i < NK + NVb) {
        int i2 = i - NK;
        int bh = i2 / (9 * DV); int r = i2 % (9 * DV); int j = r / DV; int d = r % DV;
        int tt = 491 + j;
        float v = Vt[(size_t)(bh * DV + d) * NT + tt];
        float mu = murs[MV + bh * NT + tt], rs = murs[RV + bh * NT + tt];
        outV[i2] = (v - mu) * rs * g_V[d] + be_V[d];
    }
}

// ---------------- scores partials (LN fused): spart[ch][bh][c][t] ----------------
__global__ __launch_bounds__(128) void scores_s1_k(const float* __restrict__ Qt,
    const float* __restrict__ Kt, const float* __restrict__ Kbuf,
    const float* __restrict__ murs,
    const float* __restrict__ g_Q, const float* __restrict__ be_Q,
    const float* __restrict__ g_K, const float* __restrict__ be_K,
    float* __restrict__ spart)
{
    int bh = blockIdx.x;
    int t = blockIdx.y * 128 + threadIdx.x;
    if (t >= NT) return;
    int z = blockIdx.z;
    int d0 = z * 13;
    float rsq = murs[RQ + bh * NT + t];
    float mq = -murs[MQ + bh * NT + t] * rsq;
    float s[NCTX];
    if (t >= NCTX - 1) {
        float rkc[NCTX], mkc[NCTX];
#pragma unroll
        for (int c = 0; c < NCTX; c++) {
            int tk = t - (NCTX - 1) + c;
            rkc[c] = murs[RK + bh * NT + tk];
            mkc[c] = -murs[MK + bh * NT + tk] * rkc[c];
        }
        float A[NCTX], SG = 0.f, SB = 0.f;
#pragma unroll
        for (int c = 0; c < NCTX; c++) A[c] = 0.f;
        const float* qp = Qt + ((size_t)bh * DQ + d0) * NT + t;
        const float* kp = Kt + ((size_t)bh * DQ + d0) * NT + (t - (NCTX - 1));
#pragma unroll 4
        for (int d = 0; d < 13; d++) {
            float gq = g_Q[d0 + d], bq = be_Q[d0 + d];
            float gk = g_K[d0 + d], bk = be_K[d0 + d];
            float qln = (qp[(size_t)d * NT] * rsq + mq) * gq + bq;
            float qg = qln * gk;
            SG += qg; SB += qln * bk;
            const float* kr = kp + (size_t)d * NT;
#pragma unroll
            for (int c = 0; c < NCTX; c++) A[c] += qg * kr[c];
        }
#pragma unroll
        for (int c = 0; c < NCTX; c++) s[c] = rkc[c] * A[c] + mkc[c] * SG + SB;
    } else {
#pragma unroll
        for (int c = 0; c < NCTX; c++) s[c] = 0.f;
        for (int d = 0; d < 13; d++) {
            float gq = g_Q[d0 + d], bq = be_Q[d0 + d];
            float gk = g_K[d0 + d], bk = be_K[d0 + d];
            float qln = (Qt[((size_t)bh * DQ + d0 + d) * NT + t] * rsq + mq) * gq + bq;
#pragma unroll
            for (int c = 0; c < NCTX; c++) {
                int tc = t + c;
                float kv;
                if (tc < NCTX - 1) {
                    kv = Kbuf[((size_t)bh * (NCTX - 1) + tc) * DQ + d0 + d];
                } else {
                    int tk = tc - (NCTX - 1);
                    float rk = murs[RK + bh * NT + tk];
                    float mk = murs[MK + bh * NT + tk];
                    kv = (Kt[((size_t)bh * DQ + d0 + d) * NT + tk] - mk) * rk * gk + bk;
                }
                s[c] += qln * kv;
            }
        }
    }
#pragma unroll
    for (int c = 0; c < NCTX; c++)
        spart[(size_t)((z * 32 + bh) * NCTX + c) * NT + t] = s[c];
}

// ---------------- combine + softmax: p[bh][c][t] ----------------
__global__ __launch_bounds__(128) void softmax_k(const float* __restrict__ spart,
    float* __restrict__ p)
{
    int bh = blockIdx.x;
    int t = blockIdx.y * 128 + threadIdx.x;
    if (t >= NT) return;
    float s[NCTX];
#pragma unroll
    for (int c = 0; c < NCTX; c++) s[c] = 0.f;
    for (int z = 0; z < 20; z++) {
#pragma unroll
        for (int c = 0; c < NCTX; c++)
            s[c] += spart[(size_t)((z * 32 + bh) * NCTX + c) * NT + t];
    }
    const float sc = 0.06201736729460423f; // 1/sqrt(260)
    float m = -1e30f;
#pragma unroll
    for (int c = 0; c < NCTX; c++) { s[c] *= sc; m = fmaxf(m, s[c]); }
    float den = 0.f;
#pragma unroll
    for (int c = 0; c < NCTX; c++) { s[c] = __expf(s[c] - m); den += s[c]; }
    float iden = 1.0f / den;
#pragma unroll
    for (int c = 0; c < NCTX; c++) p[(size_t)(bh * NCTX + c) * NT + t] = s[c] * iden;
}

// ---------------- Vo (LN-V fused): VoT[bh][d][t] ----------------
__global__ __launch_bounds__(128) void vo_k(const float* __restrict__ p,
    const float* __restrict__ Vt, const float* __restrict__ Vbuf,
    const float* __restrict__ murs,
    const float* __restrict__ g_V, const float* __restrict__ be_V,
    float* __restrict__ VoT)
{
    int bh = blockIdx.x;
    int t = blockIdx.y * 128 + threadIdx.x;
    if (t >= NT) return;
    int d0 = blockIdx.z * 16;
    float pc[NCTX];
#pragma unroll
    for (int c = 0; c < NCTX; c++) pc[c] = p[(size_t)(bh * NCTX + c) * NT + t];
    if (t >= NCTX - 1) {
        float prs[NCTX], Cm = 0.f, Cp = 0.f;
#pragma unroll
        for (int c = 0; c < NCTX; c++) {
            int tv = t - (NCTX - 1) + c;
            float rs = murs[RV + bh * NT + tv];
            prs[c] = pc[c] * rs;
            Cm += pc[c] * (-murs[MV + bh * NT + tv] * rs);
            Cp += pc[c];
        }
        const float* vp = Vt + ((size_t)bh * DV + d0) * NT + (t - (NCTX - 1));
        float* op = VoT + ((size_t)bh * DV + d0) * NT + t;
#pragma unroll 4
        for (int d = 0; d < 16; d++) {
            float gv = g_V[d0 + d], bv = be_V[d0 + d];
            const float* vr = vp + (size_t)d * NT;
            float A = 0.f;
#pragma unroll
            for (int c = 0; c < NCTX; c++) A += prs[c] * vr[c];
            op[(size_t)d * NT] = gv * (A + Cm) + bv * Cp;
        }
    } else {
        for (int d = 0; d < 16; d++) {
            float gv = g_V[d0 + d], bv = be_V[d0 + d];
            float acc = 0.f;
#pragma unroll
            for (int c = 0; c < NCTX; c++) {
                int tc = t + c;
                float v;
                if (tc < NCTX - 1) {
                    v = Vbuf[((size_t)bh * (NCTX - 1) + tc) * DV + d0 + d];
                } else {
                    int tv = tc - (NCTX - 1);
                    float rs = murs[RV + bh * NT + tv];
                    float mu = murs[MV + bh * NT + tv];
                    v = (Vt[((size_t)bh * DV + d0 + d) * NT + tv] - mu) * rs * gv + bv;
                }
                acc += pc[c] * v;
            }
            VoT[((size_t)bh * DV + d0 + d) * NT + t] = acc;
        }
    }
}

// ---------------- apply final LN + residual, output [b][o][f][t] ----------------
__global__ __launch_bounds__(256) void lnp_apply(const float* __restrict__ yraw,
    const float* __restrict__ x, const float* __restrict__ g, const float* __restrict__ be,
    const float* __restrict__ muA, const float* __restrict__ rstdA, float* __restrict__ out)
{
    int bo = blockIdx.x; int b = bo >> 7, o = bo & 127;
    int t = blockIdx.y * 256 + threadIdx.x;
    if (t >= NT) return;
    float mu = muA[b * NT + t], rstd = rstdA[b * NT + t];
    for (int f = 0; f < NF; f++) {
        size_t idx = (size_t)((b * NC + o) * NF + f) * NT + t;
        int i = f * NC + o;
        float v = yraw[idx];
        out[idx] = (v - mu) * rstd * g[i] + be[i] + x[idx];
    }
}

extern "C" void kernel_launch(void* const* d_in, const int* in_sizes, int n_in,
                              void* d_out, int out_size, void* d_ws, size_t ws_size,
                              hipStream_t stream) {
    const float* x    = (const float*)d_in[0];
    const float* mc   = (const float*)d_in[1];
    const float* Kbuf = (const float*)d_in[2];
    const float* Vbuf = (const float*)d_in[3];
    const float* W_Q  = (const float*)d_in[4];
    const float* b_Q  = (const float*)d_in[5];
    const float* a_Q  = (const float*)d_in[6];
    const float* g_Q  = (const float*)d_in[7];
    const float* be_Q = (const float*)d_in[8];
    const float* W_K  = (const float*)d_in[9];
    const float* b_K  = (const float*)d_in[10];
    const float* a_K  = (const float*)d_in[11];
    const float* g_K  = (const float*)d_in[12];
    const float* be_K = (const float*)d_in[13];
    const float* W_V  = (const float*)d_in[14];
    const float* b_V  = (const float*)d_in[15];
    const float* a_V  = (const float*)d_in[16];
    const float* g_V  = (const float*)d_in[17];
    const float* be_V = (const float*)d_in[18];
    const float* W_P  = (const float*)d_in[19];
    const float* b_P  = (const float*)d_in[20];
    const float* a_P  = (const float*)d_in[21];
    const float* g_P  = (const float*)d_in[22];
    const float* be_P = (const float*)d_in[23];

    float* out  = (float*)d_out;                       // (4,128,65,500)
    float* outK = out + (size_t)NB * NC * NF * NT;
    float* outV = outK + 32 * 9 * DQ;

    // QKV LN stats + mu/rs live in the head of d_out (dead until lnp_apply).
    float* stats = out;            // [sQ s2Q sK s2K sV s2V] : 96000 floats
    float* murs  = out + 96000;    // [muQ rsQ muK rsK muV rsV] : 96000 floats

    float* ws = (float*)d_ws;
    float* Qt   = ws;                                  // 4,160,000
    float* Kt   = Qt + (size_t)32 * DQ * NT;           // 4,160,000
    float* Vt   = Kt + (size_t)32 * DQ * NT;           // 16,640,000
    float* VoT  = Vt + (size_t)32 * DV * NT;           // 16,640,000
    float* pbuf = VoT + (size_t)32 * DV * NT;          // 160,000
    float* sP   = pbuf + (size_t)32 * NCTX * NT;       // 2,000
    float* s2P  = sP + NB * NT;                        // 2,000
    float* muP  = s2P + NB * NT;                       // 2,000
    float* rsP  = muP + NB * NT;                       // 2,000
    float* Wt   = rsP + NB * NT;                       // 40,960 (transposed weights)
    float* yraw  = Vt;   // alias: Vt dead after vo_k/copybuf
    float* spart = VoT;  // alias: consumed by softmax before vo_k writes VoT

    dim3 blk(256);
    dim3 blk128(128);
    const int TCH = (NT + 255) / 256;   // 2
    const int TCH4 = (NT + 127) / 128;  // 4

    hipMemsetAsync(stats, 0, 96000 * sizeof(float), stream);
    hipMemsetAsync(sP, 0, 2 * NB * NT * sizeof(float), stream);

    transW_k<<<dim3(160), blk, 0, stream>>>(W_Q, W_K, W_V, W_P, Wt);

    proj32_k<<<dim3(NB * NF, 8), blk, 0, stream>>>(x,  Wt + WTQ, b_Q, a_Q, Qt,
                                                   stats + 0,     stats + 16000);
    proj32_k<<<dim3(NB * NF, 8), blk, 0, stream>>>(mc, Wt + WTK, b_K, a_K, Kt,
                                                   stats + 32000, stats + 48000);
    projV_k <<<dim3(NB * NF, 8, 2), blk, 0, stream>>>(mc, Wt + WTV, b_V, a_V, Vt,
                                                      stats + 64000, stats + 80000);

    finqkv_k<<<dim3(188), blk, 0, stream>>>(stats, murs);

    int nbuf = 32 * 9 * DQ + 32 * 9 * DV;
    copybuf_k<<<dim3((nbuf + 255) / 256), blk, 0, stream>>>(Kt, Vt, murs,
                                                            g_K, be_K, g_V, be_V, outK, outV);

    scores_s1_k<<<dim3(32, TCH4, 20), blk128, 0, stream>>>(Qt, Kt, Kbuf, murs,
                                                           g_Q, be_Q, g_K, be_K, spart);
    softmax_k  <<<dim3(32, TCH4), blk128, 0, stream>>>(spart, pbuf);
    vo_k       <<<dim3(32, TCH4, 65), blk128, 0, stream>>>(pbuf, Vt, Vbuf, murs,
                                                           g_V, be_V, VoT);

    projP_k<<<dim3(NB * NF, 8, 2), blk, 0, stream>>>(VoT, Wt + WTP, b_P, a_P, yraw, sP, s2P);

    finp_k<<<dim3((NB * NT + 255) / 256), blk, 0, stream>>>(sP, s2P, muP, rsP);

    lnp_apply<<<dim3(NB * NC, TCH), blk, 0, stream>>>(yraw, x, g_P, be_P, muP, rsP, out);
}

// Round 6
// 717.469 us; speedup vs baseline: 1.1059x; 1.1059x over previous
//
#include <hip/hip_runtime.h>
#include <math.h>

#define NB   4
#define NT   500
#define NF   65
#define NC   128
#define NH   8
#define NE   4
#define NV   16
#define NCTX 10
#define DQ   260    // NF*NE
#define DV   1040   // NF*NV
#define DP   8320   // NF*NC

// murs layout offsets (floats): [muQ rsQ muK rsK muV rsV], each 32*500
#define MQ 0
#define RQ 16000
#define MK 32000
#define RK 48000
#define MV 64000
#define RV 80000

// Wt workspace layout (floats): [WtQ 128x32][WtK 128x32][WtV 128x128][WtP 128x128]
#define WTQ 0
#define WTK 4096
#define WTV 8192
#define WTP 24576

// ---------------- one-shot weight transpose into workspace: Wt[c][o] ----------------
__global__ __launch_bounds__(256) void transW_k(const float* __restrict__ WQ,
    const float* __restrict__ WK, const float* __restrict__ WV,
    const float* __restrict__ WP, float* __restrict__ Wt)
{
    int i = blockIdx.x * 256 + threadIdx.x;
    if (i < 4096) {
        int c = i >> 5, o = i & 31;
        Wt[WTQ + c * 32 + o] = WQ[o * 128 + c];
    } else if (i < 8192) {
        int j = i - 4096; int c = j >> 5, o = j & 31;
        Wt[WTK + c * 32 + o] = WK[o * 128 + c];
    } else if (i < 24576) {
        int j = i - 8192; int c = j >> 7, o = j & 127;
        Wt[WTV + c * 128 + o] = WV[o * 128 + c];
    } else if (i < 40960) {
        int j = i - 24576; int c = j >> 7, o = j & 127;
        Wt[WTP + c * 128 + o] = WP[o * 128 + c];
    }
}

// ---------------- fused Q+K projection: 128 -> 32, scalar-W streaming ----------------
// grid (NB*NF, 4 t-chunks, 2: z=0 Q / z=1 K). Block 256 = 4 waves; wave w owns o[8w,8w+8).
// Lane owns 2 t (float2). W read via wave-uniform s_load from Wt. No LDS, no barrier.
__global__ __launch_bounds__(256, 6) void projQK_k(const float* __restrict__ x,
    const float* __restrict__ mc, const float* __restrict__ Wt,
    const float* __restrict__ bQ, const float* __restrict__ bK,
    const float* __restrict__ aQ, const float* __restrict__ aK,
    float* __restrict__ Qt, float* __restrict__ Kt,
    float* __restrict__ stats)
{
    int z = blockIdx.z;
    const float* xin  = z ? mc : x;
    const float* wt   = Wt + (z ? WTK : WTQ);
    const float* bias = z ? bK : bQ;
    const float* ap   = z ? aK : aQ;
    float* out = z ? Kt : Qt;
    float* sS  = stats + z * 32000;
    float* sS2 = sS + 16000;
    int b = blockIdx.x / NF, f = blockIdx.x % NF;
    int w = threadIdx.x >> 6, l = threadIdx.x & 63;
    int o0 = __builtin_amdgcn_readfirstlane(w * 8);
    int t0 = blockIdx.y * 128 + l * 2;
    bool act = (t0 < NT - 1);
    int t0c = act ? t0 : NT - 2;
    const size_t xs = (size_t)NF * NT;
    const float* xp = xin + (size_t)(b * NC) * xs + (size_t)f * NT + t0c;
    float2 acc[8];
#pragma unroll
    for (int i = 0; i < 8; i++) acc[i] = make_float2(0.f, 0.f);
#pragma unroll 4
    for (int c = 0; c < NC; c++) {
        float2 xv = *(const float2*)(xp + (size_t)c * xs);
        const float* wr = wt + c * 32 + o0;   // wave-uniform -> s_load
#pragma unroll
        for (int i = 0; i < 8; i++) {
            float wv = wr[i];
            acc[i].x += wv * xv.x;
            acc[i].y += wv * xv.y;
        }
    }
    if (!act) return;
    float av = ap[0];
#pragma unroll
    for (int i = 0; i < 8; i++) {
        int o = o0 + i;
        float bo = bias[o];
        float vx = acc[i].x + bo, vy = acc[i].y + bo;
        vx = vx >= 0.f ? vx : av * vx;
        vy = vy >= 0.f ? vy : av * vy;
        acc[i].x = vx; acc[i].y = vy;
        int h = o >> 2, e = o & 3;
        *(float2*)(out + ((size_t)(b * NH + h) * DQ + f * NE + e) * NT + t0) = acc[i];
    }
#pragma unroll
    for (int hh = 0; hh < 2; hh++) {
        int h = (o0 >> 2) + hh;
        float sx = 0.f, sy = 0.f, qx = 0.f, qy = 0.f;
#pragma unroll
        for (int i = 0; i < 4; i++) {
            float2 v = acc[hh * 4 + i];
            sx += v.x; sy += v.y; qx += v.x * v.x; qy += v.y * v.y;
        }
        int base = (b * NH + h) * NT + t0;
        atomicAdd(&sS[base], sx);      atomicAdd(&sS[base + 1], sy);
        atomicAdd(&sS2[base], qx);     atomicAdd(&sS2[base + 1], qy);
    }
}

// ---------------- V projection: 128 -> 128, scalar-W streaming ----------------
// grid (NB*NF, 4, 4 o-chunks of 32). Block 256 = 4 waves x 8 o. Lane: 2 t.
__global__ __launch_bounds__(256, 6) void projV_k(const float* __restrict__ xin,
    const float* __restrict__ Wt, const float* __restrict__ bias,
    const float* __restrict__ a, float* __restrict__ out,
    float* __restrict__ sS, float* __restrict__ sS2)
{
    int b = blockIdx.x / NF, f = blockIdx.x % NF;
    int oc = blockIdx.z * 32;
    int w = threadIdx.x >> 6, l = threadIdx.x & 63;
    int o0 = __builtin_amdgcn_readfirstlane(oc + w * 8);
    int t0 = blockIdx.y * 128 + l * 2;
    bool act = (t0 < NT - 1);
    int t0c = act ? t0 : NT - 2;
    const size_t xs = (size_t)NF * NT;
    const float* xp = xin + (size_t)(b * NC) * xs + (size_t)f * NT + t0c;
    const float* wt = Wt + o0;                 // row stride 128
    float2 acc[8];
#pragma unroll
    for (int i = 0; i < 8; i++) acc[i] = make_float2(0.f, 0.f);
#pragma unroll 4
    for (int c = 0; c < NC; c++) {
        float2 xv = *(const float2*)(xp + (size_t)c * xs);
        const float* wr = wt + c * 128;        // wave-uniform -> s_load
#pragma unroll
        for (int i = 0; i < 8; i++) {
            float wv = wr[i];
            acc[i].x += wv * xv.x;
            acc[i].y += wv * xv.y;
        }
    }
    if (!act) return;
    float av = a[0];
    int h = o0 >> 4;                           // all 8 o within one head
    float sx = 0.f, sy = 0.f, qx = 0.f, qy = 0.f;
#pragma unroll
    for (int i = 0; i < 8; i++) {
        int o = o0 + i;
        float bo = bias[o];
        float vx = acc[i].x + bo, vy = acc[i].y + bo;
        vx = vx >= 0.f ? vx : av * vx;
        vy = vy >= 0.f ? vy : av * vy;
        *(float2*)(out + ((size_t)(b * NH + h) * DV + f * NV + (o & 15)) * NT + t0) = make_float2(vx, vy);
        sx += vx; sy += vy; qx += vx * vx; qy += vy * vy;
    }
    int base = (b * NH + h) * NT + t0;
    atomicAdd(&sS[base], sx);      atomicAdd(&sS[base + 1], sy);
    atomicAdd(&sS2[base], qx);     atomicAdd(&sS2[base + 1], qy);
}

// ---------------- P projection: VoT 128 -> 128, scalar-W streaming ----------------
// grid (NB*NF, 4, 4 o-chunks of 32). Input rows c = hc*16+v from VoT[bh][f*16+v][t].
__global__ __launch_bounds__(256, 6) void projP_k(const float* __restrict__ VoT,
    const float* __restrict__ Wt, const float* __restrict__ bias,
    const float* __restrict__ a, float* __restrict__ yraw,
    float* __restrict__ sP, float* __restrict__ s2P)
{
    int b = blockIdx.x / NF, f = blockIdx.x % NF;
    int oc = blockIdx.z * 32;
    int w = threadIdx.x >> 6, l = threadIdx.x & 63;
    int o0 = __builtin_amdgcn_readfirstlane(oc + w * 8);
    int t0 = blockIdx.y * 128 + l * 2;
    bool act = (t0 < NT - 1);
    int t0c = act ? t0 : NT - 2;
    const float* zb = VoT + ((size_t)(b * NH) * DV + f * NV) * NT + t0c;
    const float* wt = Wt + o0;
    float2 acc[8];
#pragma unroll
    for (int i = 0; i < 8; i++) acc[i] = make_float2(0.f, 0.f);
    for (int hc = 0; hc < NH; hc++) {
        const float* zh = zb + (size_t)hc * DV * NT;
        const float* wh = wt + hc * 16 * 128;
#pragma unroll 4
        for (int v = 0; v < NV; v++) {
            float2 xv = *(const float2*)(zh + (size_t)v * NT);
            const float* wr = wh + v * 128;    // wave-uniform -> s_load
#pragma unroll
            for (int i = 0; i < 8; i++) {
                float wv = wr[i];
                acc[i].x += wv * xv.x;
                acc[i].y += wv * xv.y;
            }
        }
    }
    if (!act) return;
    float av = a[0];
    float sx = 0.f, sy = 0.f, qx = 0.f, qy = 0.f;
#pragma unroll
    for (int i = 0; i < 8; i++) {
        int o = o0 + i;
        float bo = bias[o];
        float vx = acc[i].x + bo, vy = acc[i].y + bo;
        vx = vx >= 0.f ? vx : av * vx;
        vy = vy >= 0.f ? vy : av * vy;
        *(float2*)(yraw + ((size_t)(b * NC + o) * NF + f) * NT + t0) = make_float2(vx, vy);
        sx += vx; sy += vy; qx += vx * vx; qy += vy * vy;
    }
    int base = b * NT + t0;
    atomicAdd(&sP[base], sx);      atomicAdd(&sP[base + 1], sy);
    atomicAdd(&s2P[base], qx);     atomicAdd(&s2P[base + 1], qy);
}

// ---------------- finalize QKV stats -> mu/rs ----------------
__global__ __launch_bounds__(256) void finqkv_k(const float* __restrict__ stats,
    float* __restrict__ murs)
{
    int i = blockIdx.x * 256 + threadIdx.x;
    if (i >= 48000) return;
    int seg = i / 16000, j = i % 16000;
    float S = stats[seg * 32000 + j], S2 = stats[seg * 32000 + 16000 + j];
    float D = (seg < 2) ? 260.f : 1040.f;
    float mu = S / D;
    float var = S2 / D - mu * mu;
    murs[seg * 32000 + j] = mu;
    murs[seg * 32000 + 16000 + j] = rsqrtf(var + 1e-5f);
}

__global__ __launch_bounds__(256) void finp_k(const float* __restrict__ sP,
    const float* __restrict__ s2P, float* __restrict__ muP, float* __restrict__ rsP)
{
    int i = blockIdx.x * 256 + threadIdx.x;
    if (i >= NB * NT) return;
    float inv = 1.0f / (float)DP;
    float mu = sP[i] * inv;
    float var = s2P[i] * inv - mu * mu;
    muP[i] = mu;
    rsP[i] = rsqrtf(var + 1e-5f);
}

// ---------------- K_buf_new / V_buf_new: LN applied on the fly ----------------
__global__ void copybuf_k(const float* __restrict__ Kt, const float* __restrict__ Vt,
    const float* __restrict__ murs,
    const float* __restrict__ g_K, const float* __restrict__ be_K,
    const float* __restrict__ g_V, const float* __restrict__ be_V,
    float* __restrict__ outK, float* __restrict__ outV)
{
    int i = blockIdx.x * 256 + threadIdx.x;
    const int NK = 32 * 9 * DQ;
    const int NVb = 32 * 9 * DV;
    if (i < NK) {
        int bh = i / (9 * DQ); int r = i % (9 * DQ); int j = r / DQ; int d = r % DQ;
        int tt = 491 + j;
        float v = Kt[(size_t)(bh * DQ + d) * NT + tt];
        float mu = murs[MK + bh * NT + tt], rs = murs[RK + bh * NT + tt];
        outK[i] = (v - mu) * rs * g_K[d] + be_K[d];
    } else if (i < NK + NVb) {
        int i2 = i - NK;
        int bh = i2 / (9 * DV); int r = i2 % (9 * DV); int j = r / DV; int d = r % DV;
        int tt = 491 + j;
        float v = Vt[(size_t)(bh * DV + d) * NT + tt];
        float mu = murs[MV + bh * NT + tt], rs = murs[RV + bh * NT + tt];
        outV[i2] = (v - mu) * rs * g_V[d] + be_V[d];
    }
}

// ---------------- scores partials (LN fused): spart[ch][bh][c][t] ----------------
__global__ __launch_bounds__(128) void scores_s1_k(const float* __restrict__ Qt,
    const float* __restrict__ Kt, const float* __restrict__ Kbuf,
    const float* __restrict__ murs,
    const float* __restrict__ g_Q, const float* __restrict__ be_Q,
    const float* __restrict__ g_K, const float* __restrict__ be_K,
    float* __restrict__ spart)
{
    int bh = blockIdx.x;
    int t = blockIdx.y * 128 + threadIdx.x;
    if (t >= NT) return;
    int z = blockIdx.z;
    int d0 = z * 13;
    float rsq = murs[RQ + bh * NT + t];
    float mq = -murs[MQ + bh * NT + t] * rsq;
    float s[NCTX];
    if (t >= NCTX - 1) {
        float rkc[NCTX], mkc[NCTX];
#pragma unroll
        for (int c = 0; c < NCTX; c++) {
            int tk = t - (NCTX - 1) + c;
            rkc[c] = murs[RK + bh * NT + tk];
            mkc[c] = -murs[MK + bh * NT + tk] * rkc[c];
        }
        float A[NCTX], SG = 0.f, SB = 0.f;
#pragma unroll
        for (int c = 0; c < NCTX; c++) A[c] = 0.f;
        const float* qp = Qt + ((size_t)bh * DQ + d0) * NT + t;
        const float* kp = Kt + ((size_t)bh * DQ + d0) * NT + (t - (NCTX - 1));
#pragma unroll 4
        for (int d = 0; d < 13; d++) {
            float gq = g_Q[d0 + d], bq = be_Q[d0 + d];
            float gk = g_K[d0 + d], bk = be_K[d0 + d];
            float qln = (qp[(size_t)d * NT] * rsq + mq) * gq + bq;
            float qg = qln * gk;
            SG += qg; SB += qln * bk;
            const float* kr = kp + (size_t)d * NT;
#pragma unroll
            for (int c = 0; c < NCTX; c++) A[c] += qg * kr[c];
        }
#pragma unroll
        for (int c = 0; c < NCTX; c++) s[c] = rkc[c] * A[c] + mkc[c] * SG + SB;
    } else {
#pragma unroll
        for (int c = 0; c < NCTX; c++) s[c] = 0.f;
        for (int d = 0; d < 13; d++) {
            float gq = g_Q[d0 + d], bq = be_Q[d0 + d];
            float gk = g_K[d0 + d], bk = be_K[d0 + d];
            float qln = (Qt[((size_t)bh * DQ + d0 + d) * NT + t] * rsq + mq) * gq + bq;
#pragma unroll
            for (int c = 0; c < NCTX; c++) {
                int tc = t + c;
                float kv;
                if (tc < NCTX - 1) {
                    kv = Kbuf[((size_t)bh * (NCTX - 1) + tc) * DQ + d0 + d];
                } else {
                    int tk = tc - (NCTX - 1);
                    float rk = murs[RK + bh * NT + tk];
                    float mk = murs[MK + bh * NT + tk];
                    kv = (Kt[((size_t)bh * DQ + d0 + d) * NT + tk] - mk) * rk * gk + bk;
                }
                s[c] += qln * kv;
            }
        }
    }
#pragma unroll
    for (int c = 0; c < NCTX; c++)
        spart[(size_t)((z * 32 + bh) * NCTX + c) * NT + t] = s[c];
}

// ---------------- combine + softmax: p[bh][c][t] ----------------
__global__ __launch_bounds__(128) void softmax_k(const float* __restrict__ spart,
    float* __restrict__ p)
{
    int bh = blockIdx.x;
    int t = blockIdx.y * 128 + threadIdx.x;
    if (t >= NT) return;
    float s[NCTX];
#pragma unroll
    for (int c = 0; c < NCTX; c++) s[c] = 0.f;
    for (int z = 0; z < 20; z++) {
#pragma unroll
        for (int c = 0; c < NCTX; c++)
            s[c] += spart[(size_t)((z * 32 + bh) * NCTX + c) * NT + t];
    }
    const float sc = 0.06201736729460423f; // 1/sqrt(260)
    float m = -1e30f;
#pragma unroll
    for (int c = 0; c < NCTX; c++) { s[c] *= sc; m = fmaxf(m, s[c]); }
    float den = 0.f;
#pragma unroll
    for (int c = 0; c < NCTX; c++) { s[c] = __expf(s[c] - m); den += s[c]; }
    float iden = 1.0f / den;
#pragma unroll
    for (int c = 0; c < NCTX; c++) p[(size_t)(bh * NCTX + c) * NT + t] = s[c] * iden;
}

// ---------------- Vo (LN-V fused): VoT[bh][d][t] ----------------
__global__ __launch_bounds__(128) void vo_k(const float* __restrict__ p,
    const float* __restrict__ Vt, const float* __restrict__ Vbuf,
    const float* __restrict__ murs,
    const float* __restrict__ g_V, const float* __restrict__ be_V,
    float* __restrict__ VoT)
{
    int bh = blockIdx.x;
    int t = blockIdx.y * 128 + threadIdx.x;
    if (t >= NT) return;
    int d0 = blockIdx.z * 16;
    float pc[NCTX];
#pragma unroll
    for (int c = 0; c < NCTX; c++) pc[c] = p[(size_t)(bh * NCTX + c) * NT + t];
    if (t >= NCTX - 1) {
        float prs[NCTX], Cm = 0.f, Cp = 0.f;
#pragma unroll
        for (int c = 0; c < NCTX; c++) {
            int tv = t - (NCTX - 1) + c;
            float rs = murs[RV + bh * NT + tv];
            prs[c] = pc[c] * rs;
            Cm += pc[c] * (-murs[MV + bh * NT + tv] * rs);
            Cp += pc[c];
        }
        const float* vp = Vt + ((size_t)bh * DV + d0) * NT + (t - (NCTX - 1));
        float* op = VoT + ((size_t)bh * DV + d0) * NT + t;
#pragma unroll 4
        for (int d = 0; d < 16; d++) {
            float gv = g_V[d0 + d], bv = be_V[d0 + d];
            const float* vr = vp + (size_t)d * NT;
            float A = 0.f;
#pragma unroll
            for (int c = 0; c < NCTX; c++) A += prs[c] * vr[c];
            op[(size_t)d * NT] = gv * (A + Cm) + bv * Cp;
        }
    } else {
        for (int d = 0; d < 16; d++) {
            float gv = g_V[d0 + d], bv = be_V[d0 + d];
            float acc = 0.f;
#pragma unroll
            for (int c = 0; c < NCTX; c++) {
                int tc = t + c;
                float v;
                if (tc < NCTX - 1) {
                    v = Vbuf[((size_t)bh * (NCTX - 1) + tc) * DV + d0 + d];
                } else {
                    int tv = tc - (NCTX - 1);
                    float rs = murs[RV + bh * NT + tv];
                    float mu = murs[MV + bh * NT + tv];
                    v = (Vt[((size_t)bh * DV + d0 + d) * NT + tv] - mu) * rs * gv + bv;
                }
                acc += pc[c] * v;
            }
            VoT[((size_t)bh * DV + d0 + d) * NT + t] = acc;
        }
    }
}

// ---------------- apply final LN + residual, output [b][o][f][t] ----------------
__global__ __launch_bounds__(256) void lnp_apply(const float* __restrict__ yraw,
    const float* __restrict__ x, const float* __restrict__ g, const float* __restrict__ be,
    const float* __restrict__ muA, const float* __restrict__ rstdA, float* __restrict__ out)
{
    int bo = blockIdx.x; int b = bo >> 7, o = bo & 127;
    int t = blockIdx.y * 256 + threadIdx.x;
    if (t >= NT) return;
    float mu = muA[b * NT + t], rstd = rstdA[b * NT + t];
    for (int f = 0; f < NF; f++) {
        size_t idx = (size_t)((b * NC + o) * NF + f) * NT + t;
        int i = f * NC + o;
        float v = yraw[idx];
        out[idx] = (v - mu) * rstd * g[i] + be[i] + x[idx];
    }
}

extern "C" void kernel_launch(void* const* d_in, const int* in_sizes, int n_in,
                              void* d_out, int out_size, void* d_ws, size_t ws_size,
                              hipStream_t stream) {
    const float* x    = (const float*)d_in[0];
    const float* mc   = (const float*)d_in[1];
    const float* Kbuf = (const float*)d_in[2];
    const float* Vbuf = (const float*)d_in[3];
    const float* W_Q  = (const float*)d_in[4];
    const float* b_Q  = (const float*)d_in[5];
    const float* a_Q  = (const float*)d_in[6];
    const float* g_Q  = (const float*)d_in[7];
    const float* be_Q = (const float*)d_in[8];
    const float* W_K  = (const float*)d_in[9];
    const float* b_K  = (const float*)d_in[10];
    const float* a_K  = (const float*)d_in[11];
    const float* g_K  = (const float*)d_in[12];
    const float* be_K = (const float*)d_in[13];
    const float* W_V  = (const float*)d_in[14];
    const float* b_V  = (const float*)d_in[15];
    const float* a_V  = (const float*)d_in[16];
    const float* g_V  = (const float*)d_in[17];
    const float* be_V = (const float*)d_in[18];
    const float* W_P  = (const float*)d_in[19];
    const float* b_P  = (const float*)d_in[20];
    const float* a_P  = (const float*)d_in[21];
    const float* g_P  = (const float*)d_in[22];
    const float* be_P = (const float*)d_in[23];

    float* out  = (float*)d_out;                       // (4,128,65,500)
    float* outK = out + (size_t)NB * NC * NF * NT;
    float* outV = outK + 32 * 9 * DQ;

    // QKV LN stats + mu/rs live in the head of d_out (dead until lnp_apply).
    float* stats = out;            // [sQ s2Q sK s2K sV s2V] : 96000 floats
    float* murs  = out + 96000;    // [muQ rsQ muK rsK muV rsV] : 96000 floats

    float* ws = (float*)d_ws;
    float* Qt   = ws;                                  // 4,160,000
    float* Kt   = Qt + (size_t)32 * DQ * NT;           // 4,160,000
    float* Vt   = Kt + (size_t)32 * DQ * NT;           // 16,640,000
    float* VoT  = Vt + (size_t)32 * DV * NT;           // 16,640,000
    float* pbuf = VoT + (size_t)32 * DV * NT;          // 160,000
    float* sP   = pbuf + (size_t)32 * NCTX * NT;       // 2,000
    float* s2P  = sP + NB * NT;                        // 2,000
    float* muP  = s2P + NB * NT;                       // 2,000
    float* rsP  = muP + NB * NT;                       // 2,000
    float* Wt   = rsP + NB * NT;                       // 40,960 (transposed weights)
    float* yraw  = Vt;   // alias: Vt dead after vo_k/copybuf
    float* spart = VoT;  // alias: consumed by softmax before vo_k writes VoT

    dim3 blk(256);
    dim3 blk128(128);
    const int TCH = (NT + 255) / 256;   // 2
    const int TCH4 = (NT + 127) / 128;  // 4

    hipMemsetAsync(stats, 0, 96000 * sizeof(float), stream);
    hipMemsetAsync(sP, 0, 2 * NB * NT * sizeof(float), stream);

    transW_k<<<dim3(160), blk, 0, stream>>>(W_Q, W_K, W_V, W_P, Wt);

    projQK_k<<<dim3(NB * NF, 4, 2), blk, 0, stream>>>(x, mc, Wt, b_Q, b_K, a_Q, a_K,
                                                      Qt, Kt, stats);
    projV_k <<<dim3(NB * NF, 4, 4), blk, 0, stream>>>(mc, Wt + WTV, b_V, a_V, Vt,
                                                      stats + 64000, stats + 80000);

    finqkv_k<<<dim3(188), blk, 0, stream>>>(stats, murs);

    int nbuf = 32 * 9 * DQ + 32 * 9 * DV;
    copybuf_k<<<dim3((nbuf + 255) / 256), blk, 0, stream>>>(Kt, Vt, murs,
                                                            g_K, be_K, g_V, be_V, outK, outV);

    scores_s1_k<<<dim3(32, TCH4, 20), blk128, 0, stream>>>(Qt, Kt, Kbuf, murs,
                                                           g_Q, be_Q, g_K, be_K, spart);
    softmax_k  <<<dim3(32, TCH4), blk128, 0, stream>>>(spart, pbuf);
    vo_k       <<<dim3(32, TCH4, 65), blk128, 0, stream>>>(pbuf, Vt, Vbuf, murs,
                                                           g_V, be_V, VoT);

    projP_k<<<dim3(NB * NF, 4, 4), blk, 0, stream>>>(VoT, Wt + WTP, b_P, a_P, yraw, sP, s2P);

    finp_k<<<dim3((NB * NT + 255) / 256), blk, 0, stream>>>(sP, s2P, muP, rsP);

    lnp_apply<<<dim3(NB * NC, TCH), blk, 0, stream>>>(yraw, x, g_P, be_P, muP, rsP, out);
}

// Round 7
// 707.572 us; speedup vs baseline: 1.1214x; 1.0140x over previous
//
#include <hip/hip_runtime.h>
#include <math.h>

#define NB   4
#define NT   500
#define NF   65
#define NC   128
#define NH   8
#define NE   4
#define NV   16
#define NCTX 10
#define DQ   260    // NF*NE
#define DV   1040   // NF*NV
#define DP   8320   // NF*NC

// murs layout offsets (floats): [muQ rsQ muK rsK muV rsV], each 32*500
#define MQ 0
#define RQ 16000
#define MK 32000
#define RK 48000
#define MV 64000
#define RV 80000

// Wt workspace layout (floats): [WtQ 128x32][WtK 128x32][WtV 128x128][WtP 128x128]
#define WTQ 0
#define WTK 4096
#define WTV 8192
#define WTP 24576

// ---------------- one-shot weight transpose into workspace: Wt[c][o] ----------------
__global__ __launch_bounds__(256) void transW_k(const float* __restrict__ WQ,
    const float* __restrict__ WK, const float* __restrict__ WV,
    const float* __restrict__ WP, float* __restrict__ Wt)
{
    int i = blockIdx.x * 256 + threadIdx.x;
    if (i < 4096) {
        int c = i >> 5, o = i & 31;
        Wt[WTQ + c * 32 + o] = WQ[o * 128 + c];
    } else if (i < 8192) {
        int j = i - 4096; int c = j >> 5, o = j & 31;
        Wt[WTK + c * 32 + o] = WK[o * 128 + c];
    } else if (i < 24576) {
        int j = i - 8192; int c = j >> 7, o = j & 127;
        Wt[WTV + c * 128 + o] = WV[o * 128 + c];
    } else if (i < 40960) {
        int j = i - 24576; int c = j >> 7, o = j & 127;
        Wt[WTP + c * 128 + o] = WP[o * 128 + c];
    }
}

// ---------------- fused Q+K projection: 128 -> 32, scalar-W, 16 o/wave ----------------
// grid (4 t-chunks, NB*NF). Block 256 = 4 waves: waves 0-1 = Q (o0=0/16), waves 2-3 = K.
// Lane: 2 t. Per c: 1 float2 load + 32 FMA. No LDS, no barrier.
__global__ __launch_bounds__(256, 6) void projQK_k(const float* __restrict__ x,
    const float* __restrict__ mc, const float* __restrict__ Wt,
    const float* __restrict__ bQ, const float* __restrict__ bK,
    const float* __restrict__ aQ, const float* __restrict__ aK,
    float* __restrict__ Qt, float* __restrict__ Kt,
    float* __restrict__ stats)
{
    int w = threadIdx.x >> 6, l = threadIdx.x & 63;
    int qk = w >> 1;                       // 0=Q, 1=K (wave-uniform)
    const float* xin  = qk ? mc : x;
    const float* wt   = Wt + (qk ? WTK : WTQ);
    const float* bias = qk ? bK : bQ;
    const float* ap   = qk ? aK : aQ;
    float* out = qk ? Kt : Qt;
    float* sS  = stats + qk * 32000;
    float* sS2 = sS + 16000;
    int b = blockIdx.y / NF, f = blockIdx.y % NF;
    int o0 = __builtin_amdgcn_readfirstlane((w & 1) * 16);
    int t0 = blockIdx.x * 128 + l * 2;
    bool act = (t0 < NT - 1);
    int t0c = act ? t0 : NT - 2;
    const size_t xs = (size_t)NF * NT;
    const float* xp = xin + (size_t)(b * NC) * xs + (size_t)f * NT + t0c;
    float2 acc[16];
#pragma unroll
    for (int i = 0; i < 16; i++) acc[i] = make_float2(0.f, 0.f);
#pragma unroll 4
    for (int c = 0; c < NC; c++) {
        float2 xv = *(const float2*)(xp + (size_t)c * xs);
        const float* wr = wt + c * 32 + o0;   // wave-uniform -> s_load
#pragma unroll
        for (int i = 0; i < 16; i++) {
            float wv = wr[i];
            acc[i].x += wv * xv.x;
            acc[i].y += wv * xv.y;
        }
    }
    if (!act) return;
    float av = ap[0];
#pragma unroll
    for (int i = 0; i < 16; i++) {
        int o = o0 + i;
        float bo = bias[o];
        float vx = acc[i].x + bo, vy = acc[i].y + bo;
        vx = vx >= 0.f ? vx : av * vx;
        vy = vy >= 0.f ? vy : av * vy;
        acc[i].x = vx; acc[i].y = vy;
        int h = o >> 2, e = o & 3;
        *(float2*)(out + ((size_t)(b * NH + h) * DQ + f * NE + e) * NT + t0) = acc[i];
    }
#pragma unroll
    for (int hh = 0; hh < 4; hh++) {
        int h = (o0 >> 2) + hh;
        float sx = 0.f, sy = 0.f, qx = 0.f, qy = 0.f;
#pragma unroll
        for (int i = 0; i < 4; i++) {
            float2 v = acc[hh * 4 + i];
            sx += v.x; sy += v.y; qx += v.x * v.x; qy += v.y * v.y;
        }
        int base = (b * NH + h) * NT + t0;
        atomicAdd(&sS[base], sx);      atomicAdd(&sS[base + 1], sy);
        atomicAdd(&sS2[base], qx);     atomicAdd(&sS2[base + 1], qy);
    }
}

// ---------------- V projection: 128 -> 128, scalar-W, 16 o/wave, 2 o-chunks ----------------
// grid (8 = 4 t-chunks x 2 o-chunks, NB*NF): all blocks sharing (b,f) dispatch adjacently.
__global__ __launch_bounds__(256, 6) void projV_k(const float* __restrict__ xin,
    const float* __restrict__ Wt, const float* __restrict__ bias,
    const float* __restrict__ a, float* __restrict__ out,
    float* __restrict__ sS, float* __restrict__ sS2)
{
    int tz = blockIdx.x & 3, oz = blockIdx.x >> 2;
    int b = blockIdx.y / NF, f = blockIdx.y % NF;
    int w = threadIdx.x >> 6, l = threadIdx.x & 63;
    int o0 = __builtin_amdgcn_readfirstlane(oz * 64 + w * 16);
    int t0 = tz * 128 + l * 2;
    bool act = (t0 < NT - 1);
    int t0c = act ? t0 : NT - 2;
    const size_t xs = (size_t)NF * NT;
    const float* xp = xin + (size_t)(b * NC) * xs + (size_t)f * NT + t0c;
    const float* wt = Wt + o0;                 // row stride 128
    float2 acc[16];
#pragma unroll
    for (int i = 0; i < 16; i++) acc[i] = make_float2(0.f, 0.f);
#pragma unroll 4
    for (int c = 0; c < NC; c++) {
        float2 xv = *(const float2*)(xp + (size_t)c * xs);
        const float* wr = wt + c * 128;        // wave-uniform -> s_load
#pragma unroll
        for (int i = 0; i < 16; i++) {
            float wv = wr[i];
            acc[i].x += wv * xv.x;
            acc[i].y += wv * xv.y;
        }
    }
    if (!act) return;
    float av = a[0];
    int h = o0 >> 4;                           // 16-aligned o0: one head per wave
    float sx = 0.f, sy = 0.f, qx = 0.f, qy = 0.f;
#pragma unroll
    for (int i = 0; i < 16; i++) {
        int o = o0 + i;
        float bo = bias[o];
        float vx = acc[i].x + bo, vy = acc[i].y + bo;
        vx = vx >= 0.f ? vx : av * vx;
        vy = vy >= 0.f ? vy : av * vy;
        *(float2*)(out + ((size_t)(b * NH + h) * DV + f * NV + i) * NT + t0) = make_float2(vx, vy);
        sx += vx; sy += vy; qx += vx * vx; qy += vy * vy;
    }
    int base = (b * NH + h) * NT + t0;
    atomicAdd(&sS[base], sx);      atomicAdd(&sS[base + 1], sy);
    atomicAdd(&sS2[base], qx);     atomicAdd(&sS2[base + 1], qy);
}

// ---------------- P projection: VoT 128 -> 128, scalar-W, 16 o/wave, 2 o-chunks ----------------
__global__ __launch_bounds__(256, 6) void projP_k(const float* __restrict__ VoT,
    const float* __restrict__ Wt, const float* __restrict__ bias,
    const float* __restrict__ a, float* __restrict__ yraw,
    float* __restrict__ sP, float* __restrict__ s2P)
{
    int tz = blockIdx.x & 3, oz = blockIdx.x >> 2;
    int b = blockIdx.y / NF, f = blockIdx.y % NF;
    int w = threadIdx.x >> 6, l = threadIdx.x & 63;
    int o0 = __builtin_amdgcn_readfirstlane(oz * 64 + w * 16);
    int t0 = tz * 128 + l * 2;
    bool act = (t0 < NT - 1);
    int t0c = act ? t0 : NT - 2;
    const float* zb = VoT + ((size_t)(b * NH) * DV + f * NV) * NT + t0c;
    const float* wt = Wt + o0;
    float2 acc[16];
#pragma unroll
    for (int i = 0; i < 16; i++) acc[i] = make_float2(0.f, 0.f);
    for (int hc = 0; hc < NH; hc++) {
        const float* zh = zb + (size_t)hc * DV * NT;
        const float* wh = wt + hc * 16 * 128;
#pragma unroll 4
        for (int v = 0; v < NV; v++) {
            float2 xv = *(const float2*)(zh + (size_t)v * NT);
            const float* wr = wh + v * 128;    // wave-uniform -> s_load
#pragma unroll
            for (int i = 0; i < 16; i++) {
                float wv = wr[i];
                acc[i].x += wv * xv.x;
                acc[i].y += wv * xv.y;
            }
        }
    }
    if (!act) return;
    float av = a[0];
    float sx = 0.f, sy = 0.f, qx = 0.f, qy = 0.f;
#pragma unroll
    for (int i = 0; i < 16; i++) {
        int o = o0 + i;
        float bo = bias[o];
        float vx = acc[i].x + bo, vy = acc[i].y + bo;
        vx = vx >= 0.f ? vx : av * vx;
        vy = vy >= 0.f ? vy : av * vy;
        *(float2*)(yraw + ((size_t)(b * NC + o) * NF + f) * NT + t0) = make_float2(vx, vy);
        sx += vx; sy += vy; qx += vx * vx; qy += vy * vy;
    }
    int base = b * NT + t0;
    atomicAdd(&sP[base], sx);      atomicAdd(&sP[base + 1], sy);
    atomicAdd(&s2P[base], qx);     atomicAdd(&s2P[base + 1], qy);
}

// ---------------- finalize QKV stats -> mu/rs ----------------
__global__ __launch_bounds__(256) void finqkv_k(const float* __restrict__ stats,
    float* __restrict__ murs)
{
    int i = blockIdx.x * 256 + threadIdx.x;
    if (i >= 48000) return;
    int seg = i / 16000, j = i % 16000;
    float S = stats[seg * 32000 + j], S2 = stats[seg * 32000 + 16000 + j];
    float D = (seg < 2) ? 260.f : 1040.f;
    float mu = S / D;
    float var = S2 / D - mu * mu;
    murs[seg * 32000 + j] = mu;
    murs[seg * 32000 + 16000 + j] = rsqrtf(var + 1e-5f);
}

__global__ __launch_bounds__(256) void finp_k(const float* __restrict__ sP,
    const float* __restrict__ s2P, float* __restrict__ muP, float* __restrict__ rsP)
{
    int i = blockIdx.x * 256 + threadIdx.x;
    if (i >= NB * NT) return;
    float inv = 1.0f / (float)DP;
    float mu = sP[i] * inv;
    float var = s2P[i] * inv - mu * mu;
    muP[i] = mu;
    rsP[i] = rsqrtf(var + 1e-5f);
}

// ---------------- K_buf_new / V_buf_new: LN applied on the fly ----------------
__global__ void copybuf_k(const float* __restrict__ Kt, const float* __restrict__ Vt,
    const float* __restrict__ murs,
    const float* __restrict__ g_K, const float* __restrict__ be_K,
    const float* __restrict__ g_V, const float* __restrict__ be_V,
    float* __restrict__ outK, float* __restrict__ outV)
{
    int i = blockIdx.x * 256 + threadIdx.x;
    const int NK = 32 * 9 * DQ;
    const int NVb = 32 * 9 * DV;
    if (i < NK) {
        int bh = i / (9 * DQ); int r = i % (9 * DQ); int j = r / DQ; int d = r % DQ;
        int tt = 491 + j;
        float v = Kt[(size_t)(bh * DQ + d) * NT + tt];
        float mu = murs[MK + bh * NT + tt], rs = murs[RK + bh * NT + tt];
        outK[i] = (v - mu) * rs * g_K[d] + be_K[d];
    } else if (i < NK + NVb) {
        int i2 = i - NK;
        int bh = i2 / (9 * DV); int r = i2 % (9 * DV); int j = r / DV; int d = r % DV;
        int tt = 491 + j;
        float v = Vt[(size_t)(bh * DV + d) * NT + tt];
        float mu = murs[MV + bh * NT + tt], rs = murs[RV + bh * NT + tt];
        outV[i2] = (v - mu) * rs * g_V[d] + be_V[d];
    }
}

// ---------------- scores partials (LN fused): spart[ch][bh][c][t] ----------------
__global__ __launch_bounds__(128) void scores_s1_k(const float* __restrict__ Qt,
    const float* __restrict__ Kt, const float* __restrict__ Kbuf,
    const float* __restrict__ murs,
    const float* __restrict__ g_Q, const float* __restrict__ be_Q,
    const float* __restrict__ g_K, const float* __restrict__ be_K,
    float* __restrict__ spart)
{
    int bh = blockIdx.x;
    int t = blockIdx.y * 128 + threadIdx.x;
    if (t >= NT) return;
    int z = blockIdx.z;
    int d0 = z * 13;
    float rsq = murs[RQ + bh * NT + t];
    float mq = -murs[MQ + bh * NT + t] * rsq;
    float s[NCTX];
    if (t >= NCTX - 1) {
        float rkc[NCTX], mkc[NCTX];
#pragma unroll
        for (int c = 0; c < NCTX; c++) {
            int tk = t - (NCTX - 1) + c;
            rkc[c] = murs[RK + bh * NT + tk];
            mkc[c] = -murs[MK + bh * NT + tk] * rkc[c];
        }
        float A[NCTX], SG = 0.f, SB = 0.f;
#pragma unroll
        for (int c = 0; c < NCTX; c++) A[c] = 0.f;
        const float* qp = Qt + ((size_t)bh * DQ + d0) * NT + t;
        const float* kp = Kt + ((size_t)bh * DQ + d0) * NT + (t - (NCTX - 1));
#pragma unroll 4
        for (int d = 0; d < 13; d++) {
            float gq = g_Q[d0 + d], bq = be_Q[d0 + d];
            float gk = g_K[d0 + d], bk = be_K[d0 + d];
            float qln = (qp[(size_t)d * NT] * rsq + mq) * gq + bq;
            float qg = qln * gk;
            SG += qg; SB += qln * bk;
            const float* kr = kp + (size_t)d * NT;
#pragma unroll
            for (int c = 0; c < NCTX; c++) A[c] += qg * kr[c];
        }
#pragma unroll
        for (int c = 0; c < NCTX; c++) s[c] = rkc[c] * A[c] + mkc[c] * SG + SB;
    } else {
#pragma unroll
        for (int c = 0; c < NCTX; c++) s[c] = 0.f;
        for (int d = 0; d < 13; d++) {
            float gq = g_Q[d0 + d], bq = be_Q[d0 + d];
            float gk = g_K[d0 + d], bk = be_K[d0 + d];
            float qln = (Qt[((size_t)bh * DQ + d0 + d) * NT + t] * rsq + mq) * gq + bq;
#pragma unroll
            for (int c = 0; c < NCTX; c++) {
                int tc = t + c;
                float kv;
                if (tc < NCTX - 1) {
                    kv = Kbuf[((size_t)bh * (NCTX - 1) + tc) * DQ + d0 + d];
                } else {
                    int tk = tc - (NCTX - 1);
                    float rk = murs[RK + bh * NT + tk];
                    float mk = murs[MK + bh * NT + tk];
                    kv = (Kt[((size_t)bh * DQ + d0 + d) * NT + tk] - mk) * rk * gk + bk;
                }
                s[c] += qln * kv;
            }
        }
    }
#pragma unroll
    for (int c = 0; c < NCTX; c++)
        spart[(size_t)((z * 32 + bh) * NCTX + c) * NT + t] = s[c];
}

// ---------------- combine + softmax: p[bh][c][t] ----------------
__global__ __launch_bounds__(128) void softmax_k(const float* __restrict__ spart,
    float* __restrict__ p)
{
    int bh = blockIdx.x;
    int t = blockIdx.y * 128 + threadIdx.x;
    if (t >= NT) return;
    float s[NCTX];
#pragma unroll
    for (int c = 0; c < NCTX; c++) s[c] = 0.f;
    for (int z = 0; z < 20; z++) {
#pragma unroll
        for (int c = 0; c < NCTX; c++)
            s[c] += spart[(size_t)((z * 32 + bh) * NCTX + c) * NT + t];
    }
    const float sc = 0.06201736729460423f; // 1/sqrt(260)
    float m = -1e30f;
#pragma unroll
    for (int c = 0; c < NCTX; c++) { s[c] *= sc; m = fmaxf(m, s[c]); }
    float den = 0.f;
#pragma unroll
    for (int c = 0; c < NCTX; c++) { s[c] = __expf(s[c] - m); den += s[c]; }
    float iden = 1.0f / den;
#pragma unroll
    for (int c = 0; c < NCTX; c++) p[(size_t)(bh * NCTX + c) * NT + t] = s[c] * iden;
}

// ---------------- Vo (LN-V fused): VoT[bh][d][t] ----------------
__global__ __launch_bounds__(128) void vo_k(const float* __restrict__ p,
    const float* __restrict__ Vt, const float* __restrict__ Vbuf,
    const float* __restrict__ murs,
    const float* __restrict__ g_V, const float* __restrict__ be_V,
    float* __restrict__ VoT)
{
    int bh = blockIdx.x;
    int t = blockIdx.y * 128 + threadIdx.x;
    if (t >= NT) return;
    int d0 = blockIdx.z * 16;
    float pc[NCTX];
#pragma unroll
    for (int c = 0; c < NCTX; c++) pc[c] = p[(size_t)(bh * NCTX + c) * NT + t];
    if (t >= NCTX - 1) {
        float prs[NCTX], Cm = 0.f, Cp = 0.f;
#pragma unroll
        for (int c = 0; c < NCTX; c++) {
            int tv = t - (NCTX - 1) + c;
            float rs = murs[RV + bh * NT + tv];
            prs[c] = pc[c] * rs;
            Cm += pc[c] * (-murs[MV + bh * NT + tv] * rs);
            Cp += pc[c];
        }
        const float* vp = Vt + ((size_t)bh * DV + d0) * NT + (t - (NCTX - 1));
        float* op = VoT + ((size_t)bh * DV + d0) * NT + t;
#pragma unroll 4
        for (int d = 0; d < 16; d++) {
            float gv = g_V[d0 + d], bv = be_V[d0 + d];
            const float* vr = vp + (size_t)d * NT;
            float A = 0.f;
#pragma unroll
            for (int c = 0; c < NCTX; c++) A += prs[c] * vr[c];
            op[(size_t)d * NT] = gv * (A + Cm) + bv * Cp;
        }
    } else {
        for (int d = 0; d < 16; d++) {
            float gv = g_V[d0 + d], bv = be_V[d0 + d];
            float acc = 0.f;
#pragma unroll
            for (int c = 0; c < NCTX; c++) {
                int tc = t + c;
                float v;
                if (tc < NCTX - 1) {
                    v = Vbuf[((size_t)bh * (NCTX - 1) + tc) * DV + d0 + d];
                } else {
                    int tv = tc - (NCTX - 1);
                    float rs = murs[RV + bh * NT + tv];
                    float mu = murs[MV + bh * NT + tv];
                    v = (Vt[((size_t)bh * DV + d0 + d) * NT + tv] - mu) * rs * gv + bv;
                }
                acc += pc[c] * v;
            }
            VoT[((size_t)bh * DV + d0 + d) * NT + t] = acc;
        }
    }
}

// ---------------- apply final LN + residual, output [b][o][f][t] ----------------
__global__ __launch_bounds__(256) void lnp_apply(const float* __restrict__ yraw,
    const float* __restrict__ x, const float* __restrict__ g, const float* __restrict__ be,
    const float* __restrict__ muA, const float* __restrict__ rstdA, float* __restrict__ out)
{
    int bo = blockIdx.x; int b = bo >> 7, o = bo & 127;
    int t = blockIdx.y * 256 + threadIdx.x;
    if (t >= NT) return;
    float mu = muA[b * NT + t], rstd = rstdA[b * NT + t];
    for (int f = 0; f < NF; f++) {
        size_t idx = (size_t)((b * NC + o) * NF + f) * NT + t;
        int i = f * NC + o;
        float v = yraw[idx];
        out[idx] = (v - mu) * rstd * g[i] + be[i] + x[idx];
    }
}

extern "C" void kernel_launch(void* const* d_in, const int* in_sizes, int n_in,
                              void* d_out, int out_size, void* d_ws, size_t ws_size,
                              hipStream_t stream) {
    const float* x    = (const float*)d_in[0];
    const float* mc   = (const float*)d_in[1];
    const float* Kbuf = (const float*)d_in[2];
    const float* Vbuf = (const float*)d_in[3];
    const float* W_Q  = (const float*)d_in[4];
    const float* b_Q  = (const float*)d_in[5];
    const float* a_Q  = (const float*)d_in[6];
    const float* g_Q  = (const float*)d_in[7];
    const float* be_Q = (const float*)d_in[8];
    const float* W_K  = (const float*)d_in[9];
    const float* b_K  = (const float*)d_in[10];
    const float* a_K  = (const float*)d_in[11];
    const float* g_K  = (const float*)d_in[12];
    const float* be_K = (const float*)d_in[13];
    const float* W_V  = (const float*)d_in[14];
    const float* b_V  = (const float*)d_in[15];
    const float* a_V  = (const float*)d_in[16];
    const float* g_V  = (const float*)d_in[17];
    const float* be_V = (const float*)d_in[18];
    const float* W_P  = (const float*)d_in[19];
    const float* b_P  = (const float*)d_in[20];
    const float* a_P  = (const float*)d_in[21];
    const float* g_P  = (const float*)d_in[22];
    const float* be_P = (const float*)d_in[23];

    float* out  = (float*)d_out;                       // (4,128,65,500)
    float* outK = out + (size_t)NB * NC * NF * NT;
    float* outV = outK + 32 * 9 * DQ;

    // QKV LN stats + mu/rs live in the head of d_out (dead until lnp_apply).
    float* stats = out;            // [sQ s2Q sK s2K sV s2V] : 96000 floats
    float* murs  = out + 96000;    // [muQ rsQ muK rsK muV rsV] : 96000 floats

    float* ws = (float*)d_ws;
    float* Qt   = ws;                                  // 4,160,000
    float* Kt   = Qt + (size_t)32 * DQ * NT;           // 4,160,000
    float* Vt   = Kt + (size_t)32 * DQ * NT;           // 16,640,000
    float* VoT  = Vt + (size_t)32 * DV * NT;           // 16,640,000
    float* pbuf = VoT + (size_t)32 * DV * NT;          // 160,000
    float* sP   = pbuf + (size_t)32 * NCTX * NT;       // 2,000
    float* s2P  = sP + NB * NT;                        // 2,000
    float* muP  = s2P + NB * NT;                       // 2,000
    float* rsP  = muP + NB * NT;                       // 2,000
    float* Wt   = rsP + NB * NT;                       // 40,960 (transposed weights)
    float* yraw  = Vt;   // alias: Vt dead after vo_k/copybuf
    float* spart = VoT;  // alias: consumed by softmax before vo_k writes VoT

    dim3 blk(256);
    dim3 blk128(128);
    const int TCH = (NT + 255) / 256;   // 2
    const int TCH4 = (NT + 127) / 128;  // 4

    hipMemsetAsync(stats, 0, 96000 * sizeof(float), stream);
    hipMemsetAsync(sP, 0, 2 * NB * NT * sizeof(float), stream);

    transW_k<<<dim3(160), blk, 0, stream>>>(W_Q, W_K, W_V, W_P, Wt);

    projQK_k<<<dim3(4, NB * NF), blk, 0, stream>>>(x, mc, Wt, b_Q, b_K, a_Q, a_K,
                                                   Qt, Kt, stats);
    projV_k <<<dim3(8, NB * NF), blk, 0, stream>>>(mc, Wt + WTV, b_V, a_V, Vt,
                                                   stats + 64000, stats + 80000);

    finqkv_k<<<dim3(188), blk, 0, stream>>>(stats, murs);

    int nbuf = 32 * 9 * DQ + 32 * 9 * DV;
    copybuf_k<<<dim3((nbuf + 255) / 256), blk, 0, stream>>>(Kt, Vt, murs,
                                                            g_K, be_K, g_V, be_V, outK, outV);

    scores_s1_k<<<dim3(32, TCH4, 20), blk128, 0, stream>>>(Qt, Kt, Kbuf, murs,
                                                           g_Q, be_Q, g_K, be_K, spart);
    softmax_k  <<<dim3(32, TCH4), blk128, 0, stream>>>(spart, pbuf);
    vo_k       <<<dim3(32, TCH4, 65), blk128, 0, stream>>>(pbuf, Vt, Vbuf, murs,
                                                           g_V, be_V, VoT);

    projP_k<<<dim3(8, NB * NF), blk, 0, stream>>>(VoT, Wt + WTP, b_P, a_P, yraw, sP, s2P);

    finp_k<<<dim3((NB * NT + 255) / 256), blk, 0, stream>>>(sP, s2P, muP, rsP);

    lnp_apply<<<dim3(NB * NC, TCH), blk, 0, stream>>>(yraw, x, g_P, be_P, muP, rsP, out);
}